// Round 4
// baseline (175.358 us; speedup 1.0000x reference)
//
#include <hip/hip_runtime.h>
#include <stdint.h>

// B=8, N=1024, I=256, O=256, R=8
// out[b,dst,o] = (sum_{src,r} adj[b,src,dst,r] * f[b,src,r,o]) / clip(sum adj, 1e-16)
//
//  prep   : x fp32->bf16 [8192][256]; weight[r][i][o] -> W_t[o*8+r][i] bf16
//  k1     : f_t[b][o][k=src*8+r] = (W_t @ x^T) written via 8B vector stores
//           (A-operand = W_t rows so C-frag regs = 4 consecutive r)
//  k2     : out = (adj^T @ f_t)/denom, fused. MT=32 dst x NT=256 o, 512 thr (8 waves
//           1m x 4o x 2), NO split-K, 256 blocks (1/CU), 128 kt x (8 src x 8 r).
//           3-buffer LDS pipeline, counted s_waitcnt vmcnt(5) + raw s_barrier:
//           A(kt+2)+B(kt+2) loads stay in flight ACROSS the barrier (T3/T4).
//           A: global->reg (1 dwordx4/wave-lane, coalesced 1KB/wave) -> cvt bf16 ->
//           swizzled ds_write one kt later (T14 latency cover). B: global_load_lds
//           with pre-swizzled source. Fused fp32 denom + normalize (no k3).

typedef float          floatx4  __attribute__((ext_vector_type(4)));
typedef short          shortx8  __attribute__((ext_vector_type(8)));
typedef unsigned short ushortx4 __attribute__((ext_vector_type(4)));
typedef unsigned short ushortx8 __attribute__((ext_vector_type(8)));

__device__ __forceinline__ unsigned short f2bf(float f) {
  union { float f; unsigned int u; } v; v.f = f;
  unsigned int u = v.u + 0x7FFFu + ((v.u >> 16) & 1u);  // RNE
  return (unsigned short)(u >> 16);
}

__device__ __forceinline__ void gload16(const void* g, void* l) {
  __builtin_amdgcn_global_load_lds((__attribute__((address_space(1))) void*)g,
                                   (__attribute__((address_space(3))) void*)l,
                                   16, 0, 0);
}

#define WAIT_V5 asm volatile("s_waitcnt vmcnt(5) lgkmcnt(0)" ::: "memory")
#define WAIT_V0 asm volatile("s_waitcnt vmcnt(0) lgkmcnt(0)" ::: "memory")

// ---------------- merged prep ----------------
__global__ __launch_bounds__(256) void prep_xw(const float* __restrict__ x,
                                               const float* __restrict__ w,
                                               unsigned short* __restrict__ xbf,
                                               unsigned short* __restrict__ wt) {
  int bid = blockIdx.x;
  if (bid < 1024) {                                // x: 262144 threads x 8 elems
    int t = bid * 256 + threadIdx.x;
    const float4* p = (const float4*)x + (size_t)t * 2;
    float4 a = p[0], b4 = p[1];
    ushortx8 o;
    o[0] = f2bf(a.x);  o[1] = f2bf(a.y);  o[2] = f2bf(a.z);  o[3] = f2bf(a.w);
    o[4] = f2bf(b4.x); o[5] = f2bf(b4.y); o[6] = f2bf(b4.z); o[7] = f2bf(b4.w);
    *(ushortx8*)(xbf + (size_t)t * 8) = o;
  } else {                                         // w: 524288 scalar
    int id = (bid - 1024) * 256 + threadIdx.x;
    int r = id >> 16, i = (id >> 8) & 255, o = id & 255;
    float v = w[((size_t)(r * 256 + i) << 8) + o];
    wt[((size_t)(o * 8 + r) << 8) + i] = f2bf(v);
  }
}

// ---------------- kernel 1: f_t = x @ W (operand-swapped) ----------------
// A-operand = W_t rows (n' = o*8+r), B-operand = xbf rows (m = b*1024+src).
// D[row=n'][col=m]; thread's 4 C-regs = 4 consecutive r at fixed (o,src) -> 8B store.
__global__ __launch_bounds__(256) void k1_gemm(const unsigned short* __restrict__ xbf,
                                               const unsigned short* __restrict__ wt,
                                               unsigned short* __restrict__ ft) {
  int bid = blockIdx.x;                            // 16 p-tiles x 64 q-tiles
  int p0 = (bid & 15) * 128, q0 = (bid >> 4) * 128;
  int l = threadIdx.x & 63, w = threadIdx.x >> 6;
  int lr = l & 15, lg = l >> 4;
  int pw = p0 + (w >> 1) * 64, qw = q0 + (w & 1) * 64;

  floatx4 acc[4][4] = {};
#pragma unroll
  for (int ks = 0; ks < 8; ++ks) {                 // K = 256 = 8 * 32
    shortx8 a[4], b[4];
#pragma unroll
    for (int pi = 0; pi < 4; ++pi)
      a[pi] = *(const shortx8*)(wt + (size_t)(pw + pi * 16 + lr) * 256 + ks * 32 + lg * 8);
#pragma unroll
    for (int qi = 0; qi < 4; ++qi)
      b[qi] = *(const shortx8*)(xbf + (size_t)(qw + qi * 16 + lr) * 256 + ks * 32 + lg * 8);
#pragma unroll
    for (int pi = 0; pi < 4; ++pi)
#pragma unroll
      for (int qi = 0; qi < 4; ++qi)
        acc[pi][qi] = __builtin_amdgcn_mfma_f32_16x16x32_bf16(a[pi], b[qi], acc[pi][qi], 0, 0, 0);
  }
  // epilogue: row(n') = pw+pi*16+lg*4+reg -> o = (..)>>3, r = (lg&1)*4+reg
  //           col(m)  = qw+qi*16+lr -> (b8, src). 4 regs = ushortx4 at r-base (lg&1)*4.
#pragma unroll
  for (int pi = 0; pi < 4; ++pi) {
    int nbase = pw + pi * 16 + lg * 4;             // multiple of 4
    int o = nbase >> 3, rb = nbase & 7;            // rb in {0,4}
#pragma unroll
    for (int qi = 0; qi < 4; ++qi) {
      int m = qw + qi * 16 + lr;
      int b8 = m >> 10, src = m & 1023;
      ushortx4 h;
      h[0] = f2bf(acc[pi][qi][0]); h[1] = f2bf(acc[pi][qi][1]);
      h[2] = f2bf(acc[pi][qi][2]); h[3] = f2bf(acc[pi][qi][3]);
      *(ushortx4*)(ft + ((size_t)(b8 * 256 + o) << 13) + src * 8 + rb) = h;
    }
  }
}

// ---------------- kernel 2: out = (adj^T @ f_t)/denom, fused ----------------
#define NKT 128
#define BSZ (256 * 64)    // shorts per B buffer (32KB)
#define ASZ (32 * 64)     // shorts per A buffer (4KB)
__global__ __launch_bounds__(512) void k2_gemm(const float* __restrict__ adj,
                                               const unsigned short* __restrict__ ft,
                                               float* __restrict__ outp) {
  __shared__ __align__(16) unsigned short Blds[3 * BSZ];  // 96KB
  __shared__ __align__(16) unsigned short Alds[3 * ASZ];  // 12KB
  __shared__ float dsums[512];
  __shared__ float denr[32];

  int bid = blockIdx.x;               // 256 blocks
  int b = bid & 7;                    // XCD pin (f_t[b] = 4MB = one L2)
  int dst0 = (bid >> 3) * 32;         // 32 dst-tiles per batch

  int t = threadIdx.x, l = t & 63, w = t >> 6;     // 8 waves
  int lr = l & 15, lg = l >> 4;
  int wm = w >> 2, wo = w & 3;                     // wave -> (dst-half, o-quarter)

  // A: per kt each wave reads src row (kt*8+w): 32 dst x 8 r = 1KB coalesced
  int dst_l = (t >> 1) & 31;
  int rh = (t & 1) * 4;
  // B: pre-swizzled source chunk for linear gload_lds dest
  int csw = (l & 7) ^ (l >> 3);

  const size_t adj_b = (size_t)b << 23;
  const unsigned short* ftb = ft + ((size_t)b << 21);

  float dsum = 0.f;
  floatx4 acc[4] = {};
  float4 av1, av2;

  auto A_load = [&](int kt) -> float4 {
    return *(const float4*)(adj + adj_b + ((size_t)(kt * 8 + w) << 13)
                            + ((size_t)(dst0 + dst_l) << 3) + rh);
  };
  auto A_store = [&](float4 q, int buf) {          // src slot = w, swizzled
    dsum += q.x + q.y + q.z + q.w;
    ushortx4 h;
    h[0] = f2bf(q.x); h[1] = f2bf(q.y); h[2] = f2bf(q.z); h[3] = f2bf(q.w);
    int slot = w ^ (dst_l & 7);
    *(ushortx4*)&Alds[buf * ASZ + dst_l * 64 + slot * 8 + rh] = h;
  };
  auto B_stage = [&](int kt, int buf) {            // 4 gload16/wave, 256 o-rows
    int kbase = kt * 64;
#pragma unroll
    for (int i = 0; i < 4; ++i) {
      int orow = i * 64 + w * 8 + (l >> 3);
      const unsigned short* g = ftb + ((size_t)orow << 13) + kbase + (csw << 3);
      gload16(g, &Blds[buf * BSZ + (i * 64 + w * 8) * 64]);
    }
  };
  auto compute = [&](int buf) {
#pragma unroll
    for (int s = 0; s < 2; ++s) {
      int slotbase = s * 4 + lg;
      int arow = wm * 16 + lr;
      shortx8 af = *(const shortx8*)&Alds[buf * ASZ + arow * 64 + ((slotbase ^ (arow & 7)) << 3)];
      shortx8 bfr[4];
#pragma unroll
      for (int ni = 0; ni < 4; ++ni) {
        int oc = wo * 64 + ni * 16 + lr;
        bfr[ni] = *(const shortx8*)&Blds[buf * BSZ + oc * 64 + ((slotbase ^ (oc & 7)) << 3)];
      }
#pragma unroll
      for (int ni = 0; ni < 4; ++ni)
        acc[ni] = __builtin_amdgcn_mfma_f32_16x16x32_bf16(af, bfr[ni], acc[ni], 0, 0, 0);
    }
  };

  // ---- prologue: buf0 ready; A(1) in regs; B(1)+A(1)... = 5 in flight ----
  av1 = A_load(0);
  B_stage(0, 0);
  A_store(av1, 0);                    // waits its own load (vmcnt(4))
  av1 = A_load(1);
  B_stage(1, 1);
  WAIT_V5;                            // B(0) landed; A(1)+B(1) stay in flight
  __builtin_amdgcn_s_barrier();

  // ---- main loop: counted-vmcnt 3-buffer pipeline ----
  int c0 = 0, c1 = 1, c2 = 2;
  for (int kt = 0; kt < NKT; ++kt) {
    bool iss = (kt + 2) < NKT;
    bool st  = (kt + 1) < NKT;
    if (iss) { av2 = A_load(kt + 2); B_stage(kt + 2, c2); }
    if (st)  { A_store(av1, c1); }    // av1 = adj(kt+1), had full kt of latency cover
    compute(c0);
    if (st) {
      if (iss) { WAIT_V5; } else { WAIT_V0; }   // keep A/B(kt+2) in flight across barrier
      __builtin_amdgcn_s_barrier();
    }
    av1 = av2;
    int tmp = c0; c0 = c1; c1 = c2; c2 = tmp;
  }

  // ---- denom reduction (deterministic): 16 partials per dst row ----
  dsums[t] = dsum;
  __syncthreads();
  if (t < 32) {
    float s = 0.f;
#pragma unroll
    for (int sl = 0; sl < 8; ++sl) {
      s += dsums[sl * 64 + t * 2];
      s += dsums[sl * 64 + t * 2 + 1];
    }
    denr[t] = s;
  }
  __syncthreads();

  // ---- fused normalize + write ----
#pragma unroll
  for (int reg = 0; reg < 4; ++reg) {
    int rowl = wm * 16 + lg * 4 + reg;
    float dinv = 1.f / fmaxf(denr[rowl], 1e-16f);
    int row = dst0 + rowl;
#pragma unroll
    for (int ni = 0; ni < 4; ++ni) {
      int col = wo * 64 + ni * 16 + lr;
      outp[(((size_t)b << 10) + row) * 256 + col] = acc[ni][reg] * dinv;
    }
  }
}

// ---------------- launch ----------------
extern "C" void kernel_launch(void* const* d_in, const int* in_sizes, int n_in,
                              void* d_out, int out_size, void* d_ws, size_t ws_size,
                              hipStream_t stream) {
  const float* x   = (const float*)d_in[0];
  const float* adj = (const float*)d_in[1];
  const float* w   = (const float*)d_in[2];
  float* out = (float*)d_out;

  char* ws = (char*)d_ws;
  unsigned short* ft  = (unsigned short*)(ws);              // 32 MB
  unsigned short* xbf = (unsigned short*)(ws + 33554432);   //  4 MB
  unsigned short* wt  = (unsigned short*)(ws + 37748736);   //  1 MB

  prep_xw<<<3072, 256, 0, stream>>>(x, w, xbf, wt);
  k1_gemm<<<1024, 256, 0, stream>>>(xbf, wt, ft);
  k2_gemm<<<256, 512, 0, stream>>>(adj, ft, out);
}

// Round 5
// 161.673 us; speedup vs baseline: 1.0847x; 1.0847x over previous
//
#include <hip/hip_runtime.h>
#include <stdint.h>

// B=8, N=1024, I=256, O=256, R=8
// out[b,dst,o] = (sum_{src,r} adj[b,src,dst,r] * f[b,src,r,o]) / clip(sum adj, 1e-16)
//
//  prep   : x fp32->bf16 [8192][256]; weight[r][i][o] -> W_t[o*8+r][i] bf16
//  k1     : f_t[b][o][k=src*8+r] = W_t @ x^T (8B vector stores)
//  k2     : pout = adj^T @ f_t. 512 blocks x 256 thr (4 waves), MT=32 x NT=256,
//           KS=2, KT=64. LDS 72 KB -> 2 blocks/CU (TLP covers barrier drains; m114).
//           Plain 2-buffer __syncthreads loop, issue-early staging. Fused fp32 denom.
//  k3     : sum split-K partials, normalize.

typedef float          floatx4  __attribute__((ext_vector_type(4)));
typedef short          shortx8  __attribute__((ext_vector_type(8)));
typedef unsigned short ushortx4 __attribute__((ext_vector_type(4)));
typedef unsigned short ushortx8 __attribute__((ext_vector_type(8)));

__device__ __forceinline__ unsigned short f2bf(float f) {
  union { float f; unsigned int u; } v; v.f = f;
  unsigned int u = v.u + 0x7FFFu + ((v.u >> 16) & 1u);  // RNE
  return (unsigned short)(u >> 16);
}

__device__ __forceinline__ void gload16(const void* g, void* l) {
  __builtin_amdgcn_global_load_lds((__attribute__((address_space(1))) void*)g,
                                   (__attribute__((address_space(3))) void*)l,
                                   16, 0, 0);
}

// ---------------- merged prep ----------------
__global__ __launch_bounds__(256) void prep_xw(const float* __restrict__ x,
                                               const float* __restrict__ w,
                                               unsigned short* __restrict__ xbf,
                                               unsigned short* __restrict__ wt) {
  int bid = blockIdx.x;
  if (bid < 1024) {                                // x: 262144 threads x 8 elems
    int t = bid * 256 + threadIdx.x;
    const float4* p = (const float4*)x + (size_t)t * 2;
    float4 a = p[0], b4 = p[1];
    ushortx8 o;
    o[0] = f2bf(a.x);  o[1] = f2bf(a.y);  o[2] = f2bf(a.z);  o[3] = f2bf(a.w);
    o[4] = f2bf(b4.x); o[5] = f2bf(b4.y); o[6] = f2bf(b4.z); o[7] = f2bf(b4.w);
    *(ushortx8*)(xbf + (size_t)t * 8) = o;
  } else {                                         // w: 524288 scalar
    int id = (bid - 1024) * 256 + threadIdx.x;
    int r = id >> 16, i = (id >> 8) & 255, o = id & 255;
    float v = w[((size_t)(r * 256 + i) << 8) + o];
    wt[((size_t)(o * 8 + r) << 8) + i] = f2bf(v);
  }
}

// ---------------- kernel 1: f_t = x @ W (operand-swapped) ----------------
__global__ __launch_bounds__(256) void k1_gemm(const unsigned short* __restrict__ xbf,
                                               const unsigned short* __restrict__ wt,
                                               unsigned short* __restrict__ ft) {
  int bid = blockIdx.x;                            // 16 p-tiles x 64 q-tiles
  int p0 = (bid & 15) * 128, q0 = (bid >> 4) * 128;
  int l = threadIdx.x & 63, w = threadIdx.x >> 6;
  int lr = l & 15, lg = l >> 4;
  int pw = p0 + (w >> 1) * 64, qw = q0 + (w & 1) * 64;

  floatx4 acc[4][4] = {};
#pragma unroll
  for (int ks = 0; ks < 8; ++ks) {                 // K = 256 = 8 * 32
    shortx8 a[4], b[4];
#pragma unroll
    for (int pi = 0; pi < 4; ++pi)
      a[pi] = *(const shortx8*)(wt + (size_t)(pw + pi * 16 + lr) * 256 + ks * 32 + lg * 8);
#pragma unroll
    for (int qi = 0; qi < 4; ++qi)
      b[qi] = *(const shortx8*)(xbf + (size_t)(qw + qi * 16 + lr) * 256 + ks * 32 + lg * 8);
#pragma unroll
    for (int pi = 0; pi < 4; ++pi)
#pragma unroll
      for (int qi = 0; qi < 4; ++qi)
        acc[pi][qi] = __builtin_amdgcn_mfma_f32_16x16x32_bf16(a[pi], b[qi], acc[pi][qi], 0, 0, 0);
  }
  // row(n') = pw+pi*16+lg*4+reg -> (o, r); col(m) = qw+qi*16+lr -> (b8, src)
#pragma unroll
  for (int pi = 0; pi < 4; ++pi) {
    int nbase = pw + pi * 16 + lg * 4;
    int o = nbase >> 3, rb = nbase & 7;
#pragma unroll
    for (int qi = 0; qi < 4; ++qi) {
      int m = qw + qi * 16 + lr;
      int b8 = m >> 10, src = m & 1023;
      ushortx4 h;
      h[0] = f2bf(acc[pi][qi][0]); h[1] = f2bf(acc[pi][qi][1]);
      h[2] = f2bf(acc[pi][qi][2]); h[3] = f2bf(acc[pi][qi][3]);
      *(ushortx4*)(ft + ((size_t)(b8 * 256 + o) << 13) + src * 8 + rb) = h;
    }
  }
}

// ---------------- kernel 2: pout = adj^T @ f_t (+ denom) ----------------
// 512 blocks x 256 thr. Block: batch b, 32 dst, 256 o, K-half (64 kt x 8 src x 8 r).
#define BSZ (256 * 64)    // shorts per B buffer (32KB)
#define ASZ (32 * 64)     // shorts per A buffer (4KB)
__global__ __launch_bounds__(256, 2) void k2_gemm(const float* __restrict__ adj,
                                                  const unsigned short* __restrict__ ft,
                                                  float* __restrict__ pout,
                                                  float* __restrict__ dpart) {
  __shared__ __align__(16) unsigned short Blds[2 * BSZ];  // 64KB
  __shared__ __align__(16) unsigned short Alds[2 * ASZ];  // 8KB (overlaid post-loop)

  int bid = blockIdx.x;
  int b = bid & 7;                    // XCD pin (f_t[b] = 4MB = one L2)
  int kc = (bid >> 3) & 1;            // co-resident pair differs in dst0 -> shares B tiles
  int dst0 = (bid >> 4) * 32;

  int t = threadIdx.x, l = t & 63, w = t >> 6;     // 4 waves, wave = o-quarter
  int lr = l & 15, lg = l >> 4;

  // A-staging: thread -> dst_l (0..31), r-half, 2 src rows (w, w+4)
  int dst_l = l >> 1;
  int rh = (l & 1) * 4;
  // B-staging: pre-swizzled source chunk
  int csw = (l & 7) ^ (l >> 3);

  const size_t adj_b = (size_t)b << 23;
  const unsigned short* ftb = ft + ((size_t)b << 21);
  int src_base = kc * 512;
  const int KT = 64;

  float dsum = 0.f;
  floatx4 acc[2][4] = {};
  float4 av[2];

  auto A_load = [&](int kt, float4* v) {
#pragma unroll
    for (int j = 0; j < 2; ++j) {
      int src_l = w + j * 4;
      v[j] = *(const float4*)(adj + adj_b + ((size_t)(src_base + kt * 8 + src_l) << 13)
                              + ((size_t)(dst0 + dst_l) << 3) + rh);
    }
  };
  auto A_store = [&](int buf, const float4* v) {
#pragma unroll
    for (int j = 0; j < 2; ++j) {
      int src_l = w + j * 4;
      float4 q = v[j];
      dsum += q.x + q.y + q.z + q.w;
      ushortx4 h;
      h[0] = f2bf(q.x); h[1] = f2bf(q.y); h[2] = f2bf(q.z); h[3] = f2bf(q.w);
      int slot = src_l ^ (dst_l & 7);
      *(ushortx4*)&Alds[buf * ASZ + dst_l * 64 + slot * 8 + rh] = h;
    }
  };
  auto B_stage = [&](int kt, int buf) {            // 8 gload16/wave, 256 o-rows
    int kbase = (src_base + kt * 8) * 8;
#pragma unroll
    for (int i = 0; i < 8; ++i) {
      int orow = i * 32 + w * 8 + (l >> 3);
      const unsigned short* g = ftb + ((size_t)orow << 13) + kbase + (csw << 3);
      gload16(g, &Blds[buf * BSZ + (i * 32 + w * 8) * 64]);
    }
  };
  auto compute = [&](int buf) {
#pragma unroll
    for (int s = 0; s < 2; ++s) {
      int slotbase = s * 4 + lg;
      shortx8 af[2], bfr[4];
#pragma unroll
      for (int mi = 0; mi < 2; ++mi) {
        int arow = mi * 16 + lr;
        af[mi] = *(const shortx8*)&Alds[buf * ASZ + arow * 64 + ((slotbase ^ (arow & 7)) << 3)];
      }
#pragma unroll
      for (int ni = 0; ni < 4; ++ni) {
        int oc = w * 64 + ni * 16 + lr;
        bfr[ni] = *(const shortx8*)&Blds[buf * BSZ + oc * 64 + ((slotbase ^ (oc & 7)) << 3)];
      }
#pragma unroll
      for (int mi = 0; mi < 2; ++mi)
#pragma unroll
        for (int ni = 0; ni < 4; ++ni)
          acc[mi][ni] = __builtin_amdgcn_mfma_f32_16x16x32_bf16(af[mi], bfr[ni], acc[mi][ni], 0, 0, 0);
    }
  };

  // ---- prologue: stage kt=0 into buf 0 ----
  A_load(0, av);
  B_stage(0, 0);
  A_store(0, av);
  __syncthreads();

  // ---- main loop: 2-buffer, issue-early, occupancy covers the drain ----
  for (int kt = 0; kt < KT; ++kt) {
    int cur = kt & 1, nxt = cur ^ 1;
    bool has = (kt + 1) < KT;
    if (has) { A_load(kt + 1, av); B_stage(kt + 1, nxt); }
    compute(cur);
    if (has) A_store(nxt, av);
    __syncthreads();
  }

  // ---- denom reduction (deterministic), overlaid in Alds ----
  float* dsf = (float*)Alds;
  dsf[t] = dsum;
  __syncthreads();
  if (t < 32) {
    float s = 0.f;
#pragma unroll
    for (int sl = 0; sl < 4; ++sl) {
      s += dsf[sl * 64 + t * 2];
      s += dsf[sl * 64 + t * 2 + 1];
    }
    dsf[256 + t] = s;
    dpart[kc * 8192 + (b << 10) + dst0 + t] = s;
  }
  __syncthreads();

  // ---- write partials ----
#pragma unroll
  for (int mi = 0; mi < 2; ++mi) {
#pragma unroll
    for (int reg = 0; reg < 4; ++reg) {
      int row = dst0 + mi * 16 + lg * 4 + reg;
#pragma unroll
      for (int ni = 0; ni < 4; ++ni) {
        int col = w * 64 + ni * 16 + lr;
        pout[(size_t)kc * 2097152 + (((size_t)b << 10) + row) * 256 + col] = acc[mi][ni][reg];
      }
    }
  }
}

// ---------------- kernel 3: split-K reduce + normalize ----------------
__global__ __launch_bounds__(256) void k3_reduce(const float* __restrict__ pout,
                                                 const float* __restrict__ dpart,
                                                 float* __restrict__ outp) {
  int bid = blockIdx.x;              // b*1024 + dst
  size_t base = (size_t)bid * 256 + threadIdx.x;
  float v = pout[base] + pout[2097152 + base];
  float d = dpart[bid] + dpart[8192 + bid];
  outp[base] = v / fmaxf(d, 1e-16f);
}

// ---------------- launch ----------------
extern "C" void kernel_launch(void* const* d_in, const int* in_sizes, int n_in,
                              void* d_out, int out_size, void* d_ws, size_t ws_size,
                              hipStream_t stream) {
  const float* x   = (const float*)d_in[0];
  const float* adj = (const float*)d_in[1];
  const float* w   = (const float*)d_in[2];
  float* out = (float*)d_out;

  char* ws = (char*)d_ws;
  unsigned short* ft  = (unsigned short*)(ws);              // 32 MB
  unsigned short* xbf = (unsigned short*)(ws + 33554432);   //  4 MB
  unsigned short* wt  = (unsigned short*)(ws + 37748736);   //  1 MB
  float* pout  = (float*)(ws + 38797312);                   // 16 MB
  float* dpart = (float*)(ws + 55574528);                   // 64 KB

  prep_xw<<<3072, 256, 0, stream>>>(x, w, xbf, wt);
  k1_gemm<<<1024, 256, 0, stream>>>(xbf, wt, ft);
  k2_gemm<<<512, 256, 0, stream>>>(adj, ft, pout, dpart);
  k3_reduce<<<8192, 256, 0, stream>>>(pout, dpart, out);
}